// Round 1
// 1611.026 us; speedup vs baseline: 1.0209x; 1.0209x over previous
//
#include <hip/hip_runtime.h>
#include <cstdint>
#include <cstddef>

// Problem constants
#define NUM_C 4096
#define BB 32
#define TT 512
#define DD 128
#define MM 50

using ull = unsigned long long;

__device__ __forceinline__ float sigmoidf_(float x){ return 1.0f/(1.0f + expf(-x)); }

// Quad reduction via DPP (VALU pipe, no LDS): sum over lanes {x, x^1, x^2, x^3}
// quad_perm xor1 = [1,0,3,2] -> 0xB1 ; xor2 = [2,3,0,1] -> 0x4E
__device__ __forceinline__ float quadSum_(float v){
  int t = __builtin_amdgcn_update_dpp(0, __float_as_int(v), 0xB1, 0xF, 0xF, true);
  v += __int_as_float(t);
  t = __builtin_amdgcn_update_dpp(0, __float_as_int(v), 0x4E, 0xF, 0xF, true);
  v += __int_as_float(t);
  return v;
}

// ---------------------------------------------------------------------------
// Kernel A: parallel precompute (unchanged).
// ---------------------------------------------------------------------------
__global__ __launch_bounds__(256) void kPre(
    const int* __restrict__ q, const int* __restrict__ r,
    const float* __restrict__ k_emb, const float* __restrict__ Mk,
    const float* __restrict__ f_W, const float* __restrict__ f_b,
    const float* __restrict__ a_W, const float* __restrict__ a_b,
    float* __restrict__ wAll, ull* __restrict__ keyLo, ull* __restrict__ keyHi,
    float* __restrict__ fpre, float* __restrict__ ypre)
{
  const int b = blockIdx.y, t0 = blockIdx.x * 32, tid = threadIdx.x;
  __shared__ __align__(16) float sK[32*129];
  __shared__ int sQ[32];
  __shared__ int sR[32];
  __shared__ union UU {
    struct { float sMk[MM*129]; double sZ[32*MM]; } p2;
    float sW2[128*65];
  } u;

  if (tid < 32){ sQ[tid] = q[b*TT + t0 + tid]; sR[tid] = r[b*TT + t0 + tid]; }
  __syncthreads();
  for (int i = tid; i < 32*128; i += 256){
    int tl = i >> 7, j = i & 127;
    sK[tl*129 + j] = k_emb[(size_t)sQ[tl]*DD + j];
  }
  for (int i = tid; i < MM*128; i += 256){
    int m = i >> 7, j = i & 127;
    u.p2.sMk[m*129 + j] = Mk[i];
  }
  __syncthreads();

  for (int idx = tid; idx < 32*MM; idx += 256){
    int tl = idx / MM, m = idx - tl*MM;
    double z = 0.0;
    for (int j = 0; j < DD; j++)
      z += (double)sK[tl*129 + j] * (double)u.p2.sMk[m*129 + j];
    u.p2.sZ[tl*MM + m] = z;
  }
  __syncthreads();

  {
    int tl = tid >> 3, l8 = tid & 7;
    double zmax = -1e300;
    for (int m = l8; m < MM; m += 8) zmax = fmax(zmax, u.p2.sZ[tl*MM + m]);
    for (int s = 1; s < 8; s <<= 1) zmax = fmax(zmax, __shfl_xor(zmax, s));
    double se = 0.0;
    for (int m = l8; m < MM; m += 8){
      double e = exp(u.p2.sZ[tl*MM + m] - zmax);
      u.p2.sZ[tl*MM + m] = e;
      se += e;
    }
    for (int s = 1; s < 8; s <<= 1) se += __shfl_xor(se, s);
    double inv = 1.0 / se;
    ull klo = 0, khi = 0;
    for (int m = l8; m < MM; m += 8){
      double w = u.p2.sZ[tl*MM + m] * inv;
      wAll[((size_t)(b*TT + t0 + tl))*MM + m] = (float)w;
      double tw = fmin((w - 0.075)/(0.088 - 0.075), (1.0 - w)/(1.0 - 0.088));
      tw = fmax(tw, 0.0);
      ull iv = (tw >= 0.6) ? 2ull : ((tw >= 0.1) ? 1ull : 0ull);
      if (m < 32) klo |= iv << (2*m); else khi |= iv << (2*(m-32));
    }
    for (int s = 1; s < 8; s <<= 1){ klo |= __shfl_xor(klo, s); khi |= __shfl_xor(khi, s); }
    if (l8 == 0){ keyLo[b*TT + t0 + tl] = klo; keyHi[b*TT + t0 + tl] = khi; }
  }

  {
    const int dq = tid & 31, tq = tid >> 5;
    float acc[4][4];
    #pragma unroll
    for (int a = 0; a < 4; a++){ acc[a][0]=0.f; acc[a][1]=0.f; acc[a][2]=0.f; acc[a][3]=0.f; }
    for (int jh = 0; jh < 2; jh++){
      __syncthreads();
      for (int i = tid; i < 128*64; i += 256){
        int dd = i >> 6, jj = i & 63;
        u.sW2[dd*65 + jj] = f_W[dd*256 + 128 + jh*64 + jj];
      }
      __syncthreads();
      for (int jj = 0; jj < 64; jj++){
        float kv[4], wv[4];
        #pragma unroll
        for (int a = 0; a < 4; a++) kv[a] = sK[(tq*4 + a)*129 + jh*64 + jj];
        #pragma unroll
        for (int c = 0; c < 4; c++) wv[c] = u.sW2[(dq*4 + c)*65 + jj];
        #pragma unroll
        for (int a = 0; a < 4; a++){
          acc[a][0] += kv[a]*wv[0]; acc[a][1] += kv[a]*wv[1];
          acc[a][2] += kv[a]*wv[2]; acc[a][3] += kv[a]*wv[3];
        }
      }
    }
    #pragma unroll
    for (int a = 0; a < 4; a++){
      int tl = tq*4 + a;
      #pragma unroll
      for (int c = 0; c < 4; c++){
        int d = dq*4 + c;
        fpre[((size_t)(b*TT + t0 + tl))*DD + d] = acc[a][c] + f_b[d];
      }
    }
  }

  for (int i = tid; i < 32*DD; i += 256){
    int tl = i >> 7, d = i & 127;
    ypre[((size_t)(b*TT + t0 + tl))*DD + d] =
        a_W[(size_t)d*(NUM_C + DD) + sQ[tl]] * (float)sR[tl] + a_b[d];
  }
}

// ---------------------------------------------------------------------------
// Kernel A2: exact match search (unchanged).
// ---------------------------------------------------------------------------
__global__ __launch_bounds__(512) void kMatch(
    const ull* __restrict__ keyLo, const ull* __restrict__ keyHi, int* __restrict__ prevA)
{
  const int b = blockIdx.x, i = threadIdx.x;
  __shared__ ull slo[TT];
  __shared__ ull shi[TT];
  slo[i] = keyLo[b*TT + i];
  shi[i] = keyHi[b*TT + i];
  __syncthreads();
  const ull mylo = slo[i], myhi = shi[i];
  int found = -1;
  for (int j = i - 1; j >= 0; j--){
    if (slo[j] == mylo && shi[j] == myhi){ found = j; break; }
  }
  prevA[b*TT + i] = found;
}

// ---------------------------------------------------------------------------
// Kernel W: one-time weight products for the y-elimination:
//   Ge[d,k] = sum_j e_W[d,j]   * a_Wf[j,k]
//   Ga[d,k] = sum_j add_W[d,j] * a_Wf[j,k]
// where a_Wf[j,k] = a_W[j, NUM_C + k].
// ---------------------------------------------------------------------------
__global__ __launch_bounds__(128) void kWW(
    const float* __restrict__ e_W, const float* __restrict__ add_W,
    const float* __restrict__ a_W,
    float* __restrict__ Ge, float* __restrict__ Ga)
{
  const int d = blockIdx.x;    // 0..127
  const int k = threadIdx.x;   // 0..127
  __shared__ float se[128];
  __shared__ float sa[128];
  se[k] = e_W[(size_t)d*DD + k];
  sa[k] = add_W[(size_t)d*DD + k];
  __syncthreads();
  float ge = 0.f, ga = 0.f;
  for (int j = 0; j < DD; j++){
    float af = a_W[(size_t)j*(NUM_C + DD) + NUM_C + k];
    ge += se[j]*af;
    ga += sa[j]*af;
  }
  Ge[(size_t)d*DD + k] = ge;
  Ga[(size_t)d*DD + k] = ga;
}

// ---------------------------------------------------------------------------
// Kernel EA: parallel precompute of the ypre contribution to e/a gates:
//   eapre[row, j]      = sum_k ypre[row,k]*e_W[j,k]   + e_b[j]     (j < 128)
//   eapre[row, 128+j'] = sum_k ypre[row,k]*add_W[j',k] + add_b[j'] (j >= 128)
// kGate-style tiled GEMM (16384 x 256 x 128), fully parallel.
// ---------------------------------------------------------------------------
__global__ __launch_bounds__(256) void kEA(
    const float* __restrict__ ypre, const float* __restrict__ e_W,
    const float* __restrict__ add_W, const float* __restrict__ e_b,
    const float* __restrict__ add_b, float* __restrict__ eapre)
{
  const int jt = blockIdx.x;   // 0..3  (64 output cols each)
  const int rt = blockIdx.y;   // 0..511 (32 rows each)
  const int tid = threadIdx.x;
  __shared__ float sW[64*129];
  __shared__ float sF[32*129];
  for (int i = tid; i < 64*128; i += 256){
    int jj = i >> 7, k = i & 127;
    int j = jt*64 + jj;
    sW[jj*129 + k] = (j < 128) ? e_W[(size_t)j*DD + k] : add_W[(size_t)(j-128)*DD + k];
  }
  for (int i = tid; i < 32*128; i += 256){
    int rr = i >> 7, k = i & 127;
    sF[rr*129 + k] = ypre[(size_t)(rt*32 + rr)*DD + k];
  }
  __syncthreads();
  const int jq = tid & 31, rq = tid >> 5;
  float acc[4][2];
  #pragma unroll
  for (int a = 0; a < 4; a++){ acc[a][0] = 0.f; acc[a][1] = 0.f; }
  for (int k = 0; k < 128; k++){
    float fv[4], wv[2];
    #pragma unroll
    for (int a = 0; a < 4; a++) fv[a] = sF[(rq*4 + a)*129 + k];
    wv[0] = sW[(jq*2 + 0)*129 + k];
    wv[1] = sW[(jq*2 + 1)*129 + k];
    #pragma unroll
    for (int a = 0; a < 4; a++){ acc[a][0] += fv[a]*wv[0]; acc[a][1] += fv[a]*wv[1]; }
  }
  #pragma unroll
  for (int a = 0; a < 4; a++){
    int rowi = rt*32 + rq*4 + a;
    #pragma unroll
    for (int c = 0; c < 2; c++){
      int j = jt*64 + jq*2 + c;
      float bj = (j < 128) ? e_b[j] : add_b[j - 128];
      eapre[(size_t)rowi*256 + j] = acc[a][c] + bj;
    }
  }
}

// ---------------------------------------------------------------------------
// Kernel B (R5): memory recurrence with a 2-stage critical path.
//   y-stage eliminated:  e = sigma(f@Ge^T + epre), a = tanh(f@Ga^T + apre)
//   read-stage eliminated: read_{t+1} = r0 - e*r1 + a*s with
//     r0 = sum_m w_{t+1}[m]*mv[m],  r1 = sum_m w_{t+1}[m]*w_t[m]*mv[m],
//     s  = sum_m w_{t+1}[m]*w_t[m]   (mv = pre-update state; all off-path).
// Per step: stage F (f matvec) -> barrier -> stage EA (e/a matvecs +
// read_{t+1} + mv update) -> barrier. Chunk staging register-prefetched.
// ---------------------------------------------------------------------------
__global__ __launch_bounds__(512, 2) void kMem(
    const float* __restrict__ wAll, const float* __restrict__ fpre,
    const float* __restrict__ eapre,
    const float* __restrict__ f_W, const float* __restrict__ Ge,
    const float* __restrict__ Ga,
    const float* __restrict__ Mv0, float* __restrict__ fAll)
{
  const int b = blockIdx.x, tid = threadIdx.x;
  const int dd = tid >> 2;               // output index 0..127
  const int kc = tid & 3;                // quad lane: K-slice / m-slice selector
  const int m0 = kc*13;                  // m-chunk base (13,13,13,11)
  const int wslot = (dd >> 5)*36 + (dd & 31);   // padded write position

  // register-resident state & weights
  float mv[13];
  #pragma unroll
  for (int i = 0; i < 13; i++){
    int m = m0 + i;
    mv[i] = (m < MM) ? Mv0[(size_t)m*DD + dd] : 0.f;
  }
  float wf[32], ge[32], ga[32];
  {
    const float4* p;
    p = reinterpret_cast<const float4*>(&f_W[dd*256 + kc*32]);
    #pragma unroll
    for (int i = 0; i < 8; i++){ float4 v = p[i]; wf[4*i]=v.x; wf[4*i+1]=v.y; wf[4*i+2]=v.z; wf[4*i+3]=v.w; }
    p = reinterpret_cast<const float4*>(&Ge[(size_t)dd*DD + kc*32]);
    #pragma unroll
    for (int i = 0; i < 8; i++){ float4 v = p[i]; ge[4*i]=v.x; ge[4*i+1]=v.y; ge[4*i+2]=v.z; ge[4*i+3]=v.w; }
    p = reinterpret_cast<const float4*>(&Ga[(size_t)dd*DD + kc*32]);
    #pragma unroll
    for (int i = 0; i < 8; i++){ float4 v = p[i]; ga[4*i]=v.x; ga[4*i+1]=v.y; ga[4*i+2]=v.z; ga[4*i+3]=v.w; }
  }

  __shared__ __align__(16) float bufR[144];
  __shared__ __align__(16) float bufF[144];
  __shared__ float sW9[9*52];
  __shared__ __align__(16) float sF8[8*128];
  __shared__ __align__(16) float sEA8[8*256];
  __shared__ __align__(16) float fO8[8*128];

  const size_t base = (size_t)b*TT;
  const int rr0 = tid / 50, mm0 = tid - rr0*50;   // valid when tid < 450

  // register prefetch of chunk 0
  float4 pF = {0.f,0.f,0.f,0.f}, pEA = {0.f,0.f,0.f,0.f};
  float pW = 0.f;
  if (tid < 256) pF = reinterpret_cast<const float4*>(&fpre[base*DD])[tid];
  pEA = reinterpret_cast<const float4*>(&eapre[base*256])[tid];
  if (tid < 450) pW = wAll[(base + rr0)*MM + mm0];

  for (int t = 0; t < TT; t++){
    const int tc = t & 7;
    if (tc == 0){
      if (t){
        if (tid < 256){
          float4 v = reinterpret_cast<const float4*>(fO8)[tid];
          reinterpret_cast<float4*>(&fAll[(base + t - 8)*DD])[tid] = v;
        }
      }
      if (tid < 256) reinterpret_cast<float4*>(sF8)[tid] = pF;
      reinterpret_cast<float4*>(sEA8)[tid] = pEA;
      if (tid < 450) sW9[rr0*52 + mm0] = pW;
      if (t + 8 < TT){
        if (tid < 256) pF = reinterpret_cast<const float4*>(&fpre[(base + t + 8)*DD])[tid];
        pEA = reinterpret_cast<const float4*>(&eapre[(base + t + 8)*256])[tid];
        if (tid < 450) pW = (t + 8 + rr0 < TT) ? wAll[(base + t + 8 + rr0)*MM + mm0] : 0.f;
      }
      __syncthreads();   // R: chunk published
    }

    float wcur[13], wnxt[13];
    #pragma unroll
    for (int i = 0; i < 13; i++){
      int m = m0 + i;
      bool ok = (m < MM);
      wcur[i] = ok ? sW9[tc*52 + m] : 0.f;
      wnxt[i] = ok ? sW9[(tc+1)*52 + m] : 0.f;
    }

    if (t == 0){
      // bootstrap read_0 = sum_m w_0[m]*Mv0[m][dd]
      float r = 0.f;
      #pragma unroll
      for (int i = 0; i < 13; i++) r += wcur[i]*mv[i];
      r = quadSum_(r);
      if (kc == 0) bufR[wslot] = r;
      __syncthreads();
    }

    // ---- stage F: f = tanh(read @ f_Wr.T + fpre); r0/r1/s off-path ----
    float r0 = 0.f, r1 = 0.f, ss = 0.f;
    {
      const float4* x4 = reinterpret_cast<const float4*>(&bufR[kc*36]);
      float a0=0.f,a1=0.f,a2=0.f,a3=0.f;
      #pragma unroll
      for (int i = 0; i < 8; i++){
        float4 xv = x4[i];
        a0 += xv.x*wf[4*i]; a1 += xv.y*wf[4*i+1]; a2 += xv.z*wf[4*i+2]; a3 += xv.w*wf[4*i+3];
      }
      // off-critical-path: next-step read components from pre-update mv
      #pragma unroll
      for (int i = 0; i < 13; i++){
        float wm = wnxt[i];
        r0 += wm*mv[i];
        float ww = wm*wcur[i];
        r1 += ww*mv[i];
        ss += ww;
      }
      float s = quadSum_((a0+a1)+(a2+a3));
      float fval = tanhf(s + sF8[tc*128 + dd]);
      if (kc == 0){
        bufF[wslot] = fval;
        fO8[tc*128 + dd] = fval;
      }
      r0 = quadSum_(r0); r1 = quadSum_(r1); ss = quadSum_(ss);
    }
    __syncthreads();   // B

    // ---- stage EA: e,a directly from f; read_{t+1}; mv update ----
    {
      const float4* x4 = reinterpret_cast<const float4*>(&bufF[kc*36]);
      float e0=0.f,e1=0.f,g0=0.f,g1=0.f;
      #pragma unroll
      for (int i = 0; i < 8; i++){
        float4 xv = x4[i];
        e0 += xv.x*ge[4*i];   e1 += xv.y*ge[4*i+1];
        e0 += xv.z*ge[4*i+2]; e1 += xv.w*ge[4*i+3];
        g0 += xv.x*ga[4*i];   g1 += xv.y*ga[4*i+1];
        g0 += xv.z*ga[4*i+2]; g1 += xv.w*ga[4*i+3];
      }
      float ep = quadSum_(e0 + e1);
      float ap = quadSum_(g0 + g1);
      float e_d = sigmoidf_(ep + sEA8[tc*256 + dd]);
      float a_d = tanhf(ap + sEA8[tc*256 + 128 + dd]);
      if (kc == 0) bufR[wslot] = r0 - e_d*r1 + a_d*ss;   // read_{t+1}
      #pragma unroll
      for (int i = 0; i < 13; i++){
        float wv = wcur[i];
        mv[i] = mv[i]*(1.f - wv*e_d) + wv*a_d;
      }
    }
    __syncthreads();   // C
  }

  if (tid < 256){
    float4 v = reinterpret_cast<const float4*>(fO8)[tid];
    reinterpret_cast<float4*>(&fAll[(base + TT - 8)*DD])[tid] = v;
  }
}

// ---------------------------------------------------------------------------
// Kernel D: gpre GEMM (unchanged).
// ---------------------------------------------------------------------------
__global__ __launch_bounds__(256) void kGate(
    const float* __restrict__ fAll, const float* __restrict__ Wih,
    const float* __restrict__ bih, const float* __restrict__ bhh,
    float* __restrict__ gpre)
{
  const int jt = blockIdx.x;
  const int rt = blockIdx.y;
  const int tid = threadIdx.x;
  __shared__ float sW[64*129];
  __shared__ float sF[32*129];
  for (int i = tid; i < 64*128; i += 256){
    int jj = i >> 7, k = i & 127;
    sW[jj*129 + k] = Wih[(size_t)(jt*64 + jj)*128 + k];
  }
  for (int i = tid; i < 32*128; i += 256){
    int rr = i >> 7, k = i & 127;
    sF[rr*129 + k] = fAll[(size_t)(rt*32 + rr)*128 + k];
  }
  __syncthreads();
  const int jq = tid & 31, rq = tid >> 5;
  float acc[4][2];
  #pragma unroll
  for (int a = 0; a < 4; a++){ acc[a][0] = 0.f; acc[a][1] = 0.f; }
  for (int k = 0; k < 128; k++){
    float fv[4], wv[2];
    #pragma unroll
    for (int a = 0; a < 4; a++) fv[a] = sF[(rq*4 + a)*129 + k];
    wv[0] = sW[(jq*2 + 0)*129 + k];
    wv[1] = sW[(jq*2 + 1)*129 + k];
    #pragma unroll
    for (int a = 0; a < 4; a++){ acc[a][0] += fv[a]*wv[0]; acc[a][1] += fv[a]*wv[1]; }
  }
  #pragma unroll
  for (int a = 0; a < 4; a++){
    int rowi = rt*32 + rq*4 + a;
    #pragma unroll
    for (int c = 0; c < 2; c++){
      int j = jt*64 + jq*2 + c;
      gpre[(size_t)rowi*512 + j] = acc[a][c] + bih[j] + bhh[j];
    }
  }
}

// ---------------------------------------------------------------------------
// Kernel C (R4): LSTM, quad-mapped (unchanged).
// ---------------------------------------------------------------------------
__global__ __launch_bounds__(512, 2) void kLstm(
    const float* __restrict__ gpre, const int* __restrict__ prevA,
    const float* __restrict__ Whh,
    float* __restrict__ Hh, float* __restrict__ Ch)
{
  const int b = blockIdx.x, tid = threadIdx.x;
  const int jo = tid >> 2, kc = tid & 3;
  const int wslot = (jo >> 5)*36 + (jo & 31);

  float whh[4][32];
  #pragma unroll
  for (int g = 0; g < 4; g++){
    const float4* W4 = reinterpret_cast<const float4*>(&Whh[(size_t)(g*128 + jo)*128 + kc*32]);
    #pragma unroll
    for (int i = 0; i < 8; i++){
      float4 v = W4[i];
      whh[g][4*i] = v.x; whh[g][4*i+1] = v.y; whh[g][4*i+2] = v.z; whh[g][4*i+3] = v.w;
    }
  }

  __shared__ __align__(16) float xh[2][144];      // padded h_in broadcast (double buffer)
  __shared__ __align__(16) float gbuf[2][8*512];  // 32 KB gpre chunks
  __shared__ int spv[TT];

  const size_t base = (size_t)b*TT;
  float4 gr0, gr1;
  {
    const float4* g0 = reinterpret_cast<const float4*>(&gpre[base*512]);
    float4 a = g0[tid*2], c = g0[tid*2+1];
    float4* gb4 = reinterpret_cast<float4*>(gbuf[0]);
    gb4[tid*2] = a; gb4[tid*2+1] = c;
    const float4* g1 = reinterpret_cast<const float4*>(&gpre[(base + 8)*512]);
    gr0 = g1[tid*2]; gr1 = g1[tid*2+1];
    spv[tid] = prevA[base + tid];
    if (tid < DD) xh[0][(tid >> 5)*36 + (tid & 31)] = 0.f;
  }
  __syncthreads();

  float cin_cur = 0.f;

  for (int t = 0; t < TT; t++){
    const int tc = t & 7, p = t & 1, pc = (t >> 3) & 1;
    if (tc == 0 && t){
      __syncthreads();
      float4* gb4 = reinterpret_cast<float4*>(gbuf[pc]);
      gb4[tid*2] = gr0; gb4[tid*2+1] = gr1;
      if (t + 8 < TT){
        const float4* gp4 = reinterpret_cast<const float4*>(&gpre[(base + t + 8)*512]);
        gr0 = gp4[tid*2]; gr1 = gp4[tid*2+1];
      }
      __syncthreads();
    } else if (t) {
      __syncthreads();
    }

    const size_t row = base + t;

    int pv2 = -1; float preH = 0.f, preC = 0.f;
    if (t + 1 < TT){
      pv2 = spv[t + 1];
      if (pv2 >= 0 && pv2 < t){
        preH = Hh[(base + pv2)*DD + jo];
        preC = Ch[(base + pv2)*DD + jo];
      }
    }

    float gp0 = gbuf[pc][tc*512 + jo];
    float gp1 = gbuf[pc][tc*512 + 128 + jo];
    float gp2 = gbuf[pc][tc*512 + 256 + jo];
    float gp3 = gbuf[pc][tc*512 + 384 + jo];

    float a0=0.f,a1=0.f,a2=0.f,a3=0.f;
    {
      const float4* x4 = reinterpret_cast<const float4*>(&xh[p][kc*36]);
      #pragma unroll
      for (int i = 0; i < 8; i++){
        float4 xv = x4[i];
        a0 += xv.x*whh[0][4*i]; a0 += xv.y*whh[0][4*i+1]; a0 += xv.z*whh[0][4*i+2]; a0 += xv.w*whh[0][4*i+3];
        a1 += xv.x*whh[1][4*i]; a1 += xv.y*whh[1][4*i+1]; a1 += xv.z*whh[1][4*i+2]; a1 += xv.w*whh[1][4*i+3];
        a2 += xv.x*whh[2][4*i]; a2 += xv.y*whh[2][4*i+1]; a2 += xv.z*whh[2][4*i+2]; a2 += xv.w*whh[2][4*i+3];
        a3 += xv.x*whh[3][4*i]; a3 += xv.y*whh[3][4*i+1]; a3 += xv.z*whh[3][4*i+2]; a3 += xv.w*whh[3][4*i+3];
      }
    }
    a0 = quadSum_(a0); a1 = quadSum_(a1); a2 = quadSum_(a2); a3 = quadSum_(a3);

    const float ig = gp0 + a0, fg = gp1 + a1, gg = gp2 + a2, og = gp3 + a3;
    const float cn = sigmoidf_(fg)*cin_cur + sigmoidf_(ig)*tanhf(gg);
    const float hn = sigmoidf_(og)*tanhf(cn);

    if (kc == 0){
      Hh[row*DD + jo] = hn;
      Ch[row*DD + jo] = cn;
    }

    float hin_n, cin_n;
    if (pv2 < 0 || pv2 >= t){ hin_n = hn; cin_n = cn; }
    else                     { hin_n = preH; cin_n = preC; }
    if (kc == 0) xh[1 - p][wslot] = hin_n;
    cin_cur = cin_n;
  }
}

// ---------------------------------------------------------------------------
// Kernel E: output head (unchanged).
// ---------------------------------------------------------------------------
__global__ __launch_bounds__(256) void kOut(
    const float* __restrict__ Hh, const float* __restrict__ p_W,
    const float* __restrict__ p_b, float* __restrict__ out)
{
  const int row = blockIdx.x*16 + (threadIdx.x >> 4);
  const int l = threadIdx.x & 15;
  const float4* h4 = reinterpret_cast<const float4*>(&Hh[(size_t)row*DD + l*8]);
  const float4* w4 = reinterpret_cast<const float4*>(&p_W[l*8]);
  float4 ha = h4[0], hb = h4[1], wa = w4[0], wb = w4[1];
  float s = ha.x*wa.x + ha.y*wa.y + ha.z*wa.z + ha.w*wa.w
          + hb.x*wb.x + hb.y*wb.y + hb.z*wb.z + hb.w*wb.w;
  s += __shfl_xor(s, 1); s += __shfl_xor(s, 2);
  s += __shfl_xor(s, 4); s += __shfl_xor(s, 8);
  if (l == 0) out[row] = sigmoidf_(s + p_b[0]);
}

// ---------------------------------------------------------------------------
// Launch.
// ---------------------------------------------------------------------------
extern "C" void kernel_launch(void* const* d_in, const int* in_sizes, int n_in,
                              void* d_out, int out_size, void* d_ws, size_t ws_size,
                              hipStream_t stream) {
  const int*   q     = (const int*)  d_in[0];
  const int*   r     = (const int*)  d_in[1];
  const float* k_emb = (const float*)d_in[2];
  const float* Mk    = (const float*)d_in[3];
  const float* Mv0   = (const float*)d_in[4];
  const float* f_W   = (const float*)d_in[5];
  const float* f_b   = (const float*)d_in[6];
  const float* a_W   = (const float*)d_in[7];
  const float* a_b   = (const float*)d_in[8];
  const float* e_W   = (const float*)d_in[9];
  const float* e_b   = (const float*)d_in[10];
  const float* add_W = (const float*)d_in[11];
  const float* add_b = (const float*)d_in[12];
  const float* Wih   = (const float*)d_in[13];
  const float* Whh   = (const float*)d_in[14];
  const float* bih   = (const float*)d_in[15];
  const float* bhh   = (const float*)d_in[16];
  const float* p_W   = (const float*)d_in[17];
  const float* p_b   = (const float*)d_in[18];
  float* out = (float*)d_out;

  char* ws = (char*)d_ws;
  size_t off = 0;
  auto alloc = [&](size_t bytes) -> char* {
    char* p = ws + off;
    off += (bytes + 255) & ~(size_t)255;
    return p;
  };
  float* wAll  = (float*)alloc((size_t)BB*TT*MM*4);
  float* fpre  = (float*)alloc((size_t)BB*TT*DD*4);
  float* ypre  = (float*)alloc((size_t)BB*TT*DD*4);
  float* fAll  = (float*)alloc((size_t)BB*TT*DD*4);
  float* gpre  = (float*)alloc((size_t)BB*TT*512*4);
  float* Hh    = (float*)alloc((size_t)BB*TT*DD*4);
  float* Ch    = (float*)alloc((size_t)BB*TT*DD*4);
  ull*   keyLo = (ull*)  alloc((size_t)BB*TT*8);
  ull*   keyHi = (ull*)  alloc((size_t)BB*TT*8);
  int*   prevA = (int*)  alloc((size_t)BB*TT*4);
  float* Ge    = (float*)alloc((size_t)DD*DD*4);
  float* Ga    = (float*)alloc((size_t)DD*DD*4);
  // eapre aliases gpre: lifetimes are disjoint
  // (eapre: [kEA, kMem]; gpre: [kGate, kLstm]).
  float* eapre = gpre;
  (void)ws_size; (void)in_sizes; (void)n_in; (void)out_size;

  kPre  <<<dim3(16, 32), 256, 0, stream>>>(q, r, k_emb, Mk, f_W, f_b, a_W, a_b,
                                           wAll, keyLo, keyHi, fpre, ypre);
  kWW   <<<128, 128, 0, stream>>>(e_W, add_W, a_W, Ge, Ga);
  kEA   <<<dim3(4, 512), 256, 0, stream>>>(ypre, e_W, add_W, e_b, add_b, eapre);
  kMatch<<<32, 512, 0, stream>>>(keyLo, keyHi, prevA);
  kMem  <<<32, 512, 0, stream>>>(wAll, fpre, eapre, f_W, Ge, Ga, Mv0, fAll);
  kGate <<<dim3(8, 512), 256, 0, stream>>>(fAll, Wih, bih, bhh, gpre);
  kLstm <<<32, 512, 0, stream>>>(gpre, prevA, Whh, Hh, Ch);
  kOut  <<<(BB*TT)/16, 256, 0, stream>>>(Hh, p_W, p_b, out);
}

// Round 2
// 1235.260 us; speedup vs baseline: 1.3314x; 1.3042x over previous
//
#include <hip/hip_runtime.h>
#include <cstdint>
#include <cstddef>

// Problem constants
#define NUM_C 4096
#define BB 32
#define TT 512
#define DD 128
#define MM 50

using ull = unsigned long long;

__device__ __forceinline__ float sigmoidf_(float x){ return 1.0f/(1.0f + expf(-x)); }

// Fast transcendentals on the serial critical path: v_exp_f32 / v_rcp_f32
// (~1 ulp each, ~1e-7 rel err) instead of libm tanhf/expf (25-40 instr).
__device__ __forceinline__ float fexp2_(float x){ return __builtin_amdgcn_exp2f(x); }
__device__ __forceinline__ float frcp_(float x){ return __builtin_amdgcn_rcpf(x); }
__device__ __forceinline__ float fast_sig_(float x){
  return frcp_(1.0f + fexp2_(-1.44269504088896341f*x));
}
__device__ __forceinline__ float fast_tanh_(float x){
  float t = fexp2_(2.88539008177792681f*x);     // e^(2x)
  return 1.0f - 2.0f*frcp_(t + 1.0f);           // x->-inf: -1 ; x->+inf: +1
}

// Quad reduction via DPP (VALU pipe, no LDS): sum over lanes {x, x^1, x^2, x^3}
__device__ __forceinline__ float quadSum_(float v){
  int t = __builtin_amdgcn_update_dpp(0, __float_as_int(v), 0xB1, 0xF, 0xF, true);
  v += __int_as_float(t);
  t = __builtin_amdgcn_update_dpp(0, __float_as_int(v), 0x4E, 0xF, 0xF, true);
  v += __int_as_float(t);
  return v;
}

// ---------------------------------------------------------------------------
// Kernel A: parallel precompute (unchanged).
// ---------------------------------------------------------------------------
__global__ __launch_bounds__(256) void kPre(
    const int* __restrict__ q, const int* __restrict__ r,
    const float* __restrict__ k_emb, const float* __restrict__ Mk,
    const float* __restrict__ f_W, const float* __restrict__ f_b,
    const float* __restrict__ a_W, const float* __restrict__ a_b,
    float* __restrict__ wAll, ull* __restrict__ keyLo, ull* __restrict__ keyHi,
    float* __restrict__ fpre, float* __restrict__ ypre)
{
  const int b = blockIdx.y, t0 = blockIdx.x * 32, tid = threadIdx.x;
  __shared__ __align__(16) float sK[32*129];
  __shared__ int sQ[32];
  __shared__ int sR[32];
  __shared__ union UU {
    struct { float sMk[MM*129]; double sZ[32*MM]; } p2;
    float sW2[128*65];
  } u;

  if (tid < 32){ sQ[tid] = q[b*TT + t0 + tid]; sR[tid] = r[b*TT + t0 + tid]; }
  __syncthreads();
  for (int i = tid; i < 32*128; i += 256){
    int tl = i >> 7, j = i & 127;
    sK[tl*129 + j] = k_emb[(size_t)sQ[tl]*DD + j];
  }
  for (int i = tid; i < MM*128; i += 256){
    int m = i >> 7, j = i & 127;
    u.p2.sMk[m*129 + j] = Mk[i];
  }
  __syncthreads();

  for (int idx = tid; idx < 32*MM; idx += 256){
    int tl = idx / MM, m = idx - tl*MM;
    double z = 0.0;
    for (int j = 0; j < DD; j++)
      z += (double)sK[tl*129 + j] * (double)u.p2.sMk[m*129 + j];
    u.p2.sZ[tl*MM + m] = z;
  }
  __syncthreads();

  {
    int tl = tid >> 3, l8 = tid & 7;
    double zmax = -1e300;
    for (int m = l8; m < MM; m += 8) zmax = fmax(zmax, u.p2.sZ[tl*MM + m]);
    for (int s = 1; s < 8; s <<= 1) zmax = fmax(zmax, __shfl_xor(zmax, s));
    double se = 0.0;
    for (int m = l8; m < MM; m += 8){
      double e = exp(u.p2.sZ[tl*MM + m] - zmax);
      u.p2.sZ[tl*MM + m] = e;
      se += e;
    }
    for (int s = 1; s < 8; s <<= 1) se += __shfl_xor(se, s);
    double inv = 1.0 / se;
    ull klo = 0, khi = 0;
    for (int m = l8; m < MM; m += 8){
      double w = u.p2.sZ[tl*MM + m] * inv;
      wAll[((size_t)(b*TT + t0 + tl))*MM + m] = (float)w;
      double tw = fmin((w - 0.075)/(0.088 - 0.075), (1.0 - w)/(1.0 - 0.088));
      tw = fmax(tw, 0.0);
      ull iv = (tw >= 0.6) ? 2ull : ((tw >= 0.1) ? 1ull : 0ull);
      if (m < 32) klo |= iv << (2*m); else khi |= iv << (2*(m-32));
    }
    for (int s = 1; s < 8; s <<= 1){ klo |= __shfl_xor(klo, s); khi |= __shfl_xor(khi, s); }
    if (l8 == 0){ keyLo[b*TT + t0 + tl] = klo; keyHi[b*TT + t0 + tl] = khi; }
  }

  {
    const int dq = tid & 31, tq = tid >> 5;
    float acc[4][4];
    #pragma unroll
    for (int a = 0; a < 4; a++){ acc[a][0]=0.f; acc[a][1]=0.f; acc[a][2]=0.f; acc[a][3]=0.f; }
    for (int jh = 0; jh < 2; jh++){
      __syncthreads();
      for (int i = tid; i < 128*64; i += 256){
        int dd = i >> 6, jj = i & 63;
        u.sW2[dd*65 + jj] = f_W[dd*256 + 128 + jh*64 + jj];
      }
      __syncthreads();
      for (int jj = 0; jj < 64; jj++){
        float kv[4], wv[4];
        #pragma unroll
        for (int a = 0; a < 4; a++) kv[a] = sK[(tq*4 + a)*129 + jh*64 + jj];
        #pragma unroll
        for (int c = 0; c < 4; c++) wv[c] = u.sW2[(dq*4 + c)*65 + jj];
        #pragma unroll
        for (int a = 0; a < 4; a++){
          acc[a][0] += kv[a]*wv[0]; acc[a][1] += kv[a]*wv[1];
          acc[a][2] += kv[a]*wv[2]; acc[a][3] += kv[a]*wv[3];
        }
      }
    }
    #pragma unroll
    for (int a = 0; a < 4; a++){
      int tl = tq*4 + a;
      #pragma unroll
      for (int c = 0; c < 4; c++){
        int d = dq*4 + c;
        fpre[((size_t)(b*TT + t0 + tl))*DD + d] = acc[a][c] + f_b[d];
      }
    }
  }

  for (int i = tid; i < 32*DD; i += 256){
    int tl = i >> 7, d = i & 127;
    ypre[((size_t)(b*TT + t0 + tl))*DD + d] =
        a_W[(size_t)d*(NUM_C + DD) + sQ[tl]] * (float)sR[tl] + a_b[d];
  }
}

// ---------------------------------------------------------------------------
// Kernel A2: exact match search (unchanged).
// ---------------------------------------------------------------------------
__global__ __launch_bounds__(512) void kMatch(
    const ull* __restrict__ keyLo, const ull* __restrict__ keyHi, int* __restrict__ prevA)
{
  const int b = blockIdx.x, i = threadIdx.x;
  __shared__ ull slo[TT];
  __shared__ ull shi[TT];
  slo[i] = keyLo[b*TT + i];
  shi[i] = keyHi[b*TT + i];
  __syncthreads();
  const ull mylo = slo[i], myhi = shi[i];
  int found = -1;
  for (int j = i - 1; j >= 0; j--){
    if (slo[j] == mylo && shi[j] == myhi){ found = j; break; }
  }
  prevA[b*TT + i] = found;
}

// ---------------------------------------------------------------------------
// Kernel W: one-time weight products (unchanged).
// ---------------------------------------------------------------------------
__global__ __launch_bounds__(128) void kWW(
    const float* __restrict__ e_W, const float* __restrict__ add_W,
    const float* __restrict__ a_W,
    float* __restrict__ Ge, float* __restrict__ Ga)
{
  const int d = blockIdx.x;    // 0..127
  const int k = threadIdx.x;   // 0..127
  __shared__ float se[128];
  __shared__ float sa[128];
  se[k] = e_W[(size_t)d*DD + k];
  sa[k] = add_W[(size_t)d*DD + k];
  __syncthreads();
  float ge = 0.f, ga = 0.f;
  for (int j = 0; j < DD; j++){
    float af = a_W[(size_t)j*(NUM_C + DD) + NUM_C + k];
    ge += se[j]*af;
    ga += sa[j]*af;
  }
  Ge[(size_t)d*DD + k] = ge;
  Ga[(size_t)d*DD + k] = ga;
}

// ---------------------------------------------------------------------------
// Kernel EA: eapre GEMM (unchanged).
// ---------------------------------------------------------------------------
__global__ __launch_bounds__(256) void kEA(
    const float* __restrict__ ypre, const float* __restrict__ e_W,
    const float* __restrict__ add_W, const float* __restrict__ e_b,
    const float* __restrict__ add_b, float* __restrict__ eapre)
{
  const int jt = blockIdx.x;   // 0..3  (64 output cols each)
  const int rt = blockIdx.y;   // 0..511 (32 rows each)
  const int tid = threadIdx.x;
  __shared__ float sW[64*129];
  __shared__ float sF[32*129];
  for (int i = tid; i < 64*128; i += 256){
    int jj = i >> 7, k = i & 127;
    int j = jt*64 + jj;
    sW[jj*129 + k] = (j < 128) ? e_W[(size_t)j*DD + k] : add_W[(size_t)(j-128)*DD + k];
  }
  for (int i = tid; i < 32*128; i += 256){
    int rr = i >> 7, k = i & 127;
    sF[rr*129 + k] = ypre[(size_t)(rt*32 + rr)*DD + k];
  }
  __syncthreads();
  const int jq = tid & 31, rq = tid >> 5;
  float acc[4][2];
  #pragma unroll
  for (int a = 0; a < 4; a++){ acc[a][0] = 0.f; acc[a][1] = 0.f; }
  for (int k = 0; k < 128; k++){
    float fv[4], wv[2];
    #pragma unroll
    for (int a = 0; a < 4; a++) fv[a] = sF[(rq*4 + a)*129 + k];
    wv[0] = sW[(jq*2 + 0)*129 + k];
    wv[1] = sW[(jq*2 + 1)*129 + k];
    #pragma unroll
    for (int a = 0; a < 4; a++){ acc[a][0] += fv[a]*wv[0]; acc[a][1] += fv[a]*wv[1]; }
  }
  #pragma unroll
  for (int a = 0; a < 4; a++){
    int rowi = rt*32 + rq*4 + a;
    #pragma unroll
    for (int c = 0; c < 2; c++){
      int j = jt*64 + jq*2 + c;
      float bj = (j < 128) ? e_b[j] : add_b[j - 128];
      eapre[(size_t)rowi*256 + j] = acc[a][c] + bj;
    }
  }
}

// ---------------------------------------------------------------------------
// Kernel SS: ss[b][t] = sum_m w[b][t][m]*w[b][t+1][m]  (ss[b][TT-1] = 0).
// dd-independent part of the read update, computed once in parallel instead
// of 128x redundantly on kMem's critical path.
// ---------------------------------------------------------------------------
__global__ __launch_bounds__(512) void kSS(
    const float* __restrict__ wAll, float* __restrict__ ssAll)
{
  const int b = blockIdx.x, t = threadIdx.x;
  float s = 0.f;
  if (t < TT - 1){
    const float* w0 = &wAll[((size_t)b*TT + t)*MM];
    #pragma unroll
    for (int m = 0; m < MM; m++) s += w0[m]*w0[m + MM];
  }
  ssAll[(size_t)b*TT + t] = s;
}

// ---------------------------------------------------------------------------
// Kernel B (R6): memory recurrence, VALU-diet edition.
//  - chunked loop with #pragma unroll 8: immediate LDS offsets, free w-reg
//    rotation (wnxt of step t becomes wcur of t+1: 13 ds_reads saved/step)
//  - sW9 rows zero-padded to 52: unconditional loads, no cndmask
//  - ss precomputed (kSS): r-path is r0,r1 only
//  - fast tanh/sigmoid (v_exp/v_rcp)
//  - amdgpu_waves_per_eu(2,2): only 1 block/CU anyway (32 blocks); let the
//    allocator keep wf/ge/ga/mv in real VGPRs (<=256) instead of AGPR moves
// ---------------------------------------------------------------------------
__global__ __launch_bounds__(512, 2) __attribute__((amdgpu_waves_per_eu(2, 2)))
void kMem(
    const float* __restrict__ wAll, const float* __restrict__ fpre,
    const float* __restrict__ eapre,
    const float* __restrict__ f_W, const float* __restrict__ Ge,
    const float* __restrict__ Ga,
    const float* __restrict__ Mv0, const float* __restrict__ ssAll,
    float* __restrict__ fAll)
{
  const int b = blockIdx.x, tid = threadIdx.x;
  const int dd = tid >> 2;               // output index 0..127
  const int kc = tid & 3;                // quad lane: K-slice / m-slice selector
  const int m0 = kc*13;                  // m-chunk base (13,13,13,11 + zero pad)
  const int wslot = (dd >> 5)*36 + (dd & 31);   // padded write position

  // register-resident state & weights
  float mv[13];
  #pragma unroll
  for (int i = 0; i < 13; i++){
    int m = m0 + i;
    mv[i] = (m < MM) ? Mv0[(size_t)m*DD + dd] : 0.f;
  }
  float wf[32], ge[32], ga[32];
  {
    const float4* p;
    p = reinterpret_cast<const float4*>(&f_W[dd*256 + kc*32]);
    #pragma unroll
    for (int i = 0; i < 8; i++){ float4 v = p[i]; wf[4*i]=v.x; wf[4*i+1]=v.y; wf[4*i+2]=v.z; wf[4*i+3]=v.w; }
    p = reinterpret_cast<const float4*>(&Ge[(size_t)dd*DD + kc*32]);
    #pragma unroll
    for (int i = 0; i < 8; i++){ float4 v = p[i]; ge[4*i]=v.x; ge[4*i+1]=v.y; ge[4*i+2]=v.z; ge[4*i+3]=v.w; }
    p = reinterpret_cast<const float4*>(&Ga[(size_t)dd*DD + kc*32]);
    #pragma unroll
    for (int i = 0; i < 8; i++){ float4 v = p[i]; ga[4*i]=v.x; ga[4*i+1]=v.y; ga[4*i+2]=v.z; ga[4*i+3]=v.w; }
  }

  __shared__ __align__(16) float bufR[144];
  __shared__ __align__(16) float bufF[144];
  __shared__ float sW9[9*52];            // rows padded to 52; cols 50,51 == 0
  __shared__ float sS8[8];
  __shared__ __align__(16) float sF8[8*128];
  __shared__ __align__(16) float sEA8[8*256];
  __shared__ __align__(16) float fO8[8*128];

  const size_t base = (size_t)b*TT;
  const int rr0 = tid / 50, mm0 = tid - rr0*50;   // valid when tid < 450

  // zero the pad columns once (publishes never touch cols 50,51)
  if (tid < 18){ int rr = tid >> 1; sW9[rr*52 + 50 + (tid & 1)] = 0.f; }

  // register prefetch of chunk 0
  float4 pF = {0.f,0.f,0.f,0.f}, pEA = {0.f,0.f,0.f,0.f};
  float pW = 0.f, pS = 0.f;
  if (tid < 256) pF = reinterpret_cast<const float4*>(&fpre[base*DD])[tid];
  pEA = reinterpret_cast<const float4*>(&eapre[base*256])[tid];
  if (tid < 450) pW = wAll[(base + rr0)*MM + mm0];
  if (tid < 8)  pS = ssAll[base + tid];

  float wreg[13];   // w_t for the current step (rotated from wnxt)

  for (int ch = 0; ch < TT/8; ch++){
    const int t0 = ch*8;
    if (ch){
      if (tid < 256){
        float4 v = reinterpret_cast<const float4*>(fO8)[tid];
        reinterpret_cast<float4*>(&fAll[(base + t0 - 8)*DD])[tid] = v;
      }
    }
    if (tid < 256) reinterpret_cast<float4*>(sF8)[tid] = pF;
    reinterpret_cast<float4*>(sEA8)[tid] = pEA;
    if (tid < 450) sW9[rr0*52 + mm0] = pW;
    if (tid < 8) sS8[tid] = pS;
    if (t0 + 8 < TT){
      if (tid < 256) pF = reinterpret_cast<const float4*>(&fpre[(base + t0 + 8)*DD])[tid];
      pEA = reinterpret_cast<const float4*>(&eapre[(base + t0 + 8)*256])[tid];
      if (tid < 450) pW = (t0 + 8 + rr0 < TT) ? wAll[(base + t0 + 8 + rr0)*MM + mm0] : 0.f;
      if (tid < 8) pS = ssAll[base + t0 + 8 + tid];
    }
    __syncthreads();   // R: chunk published

    if (ch == 0){
      // bootstrap: wreg = w_0 ; read_0 = sum_m w_0[m]*Mv0[m][dd]
      #pragma unroll
      for (int i = 0; i < 13; i++) wreg[i] = sW9[m0 + i];
      float r = 0.f;
      #pragma unroll
      for (int i = 0; i < 13; i++) r += wreg[i]*mv[i];
      r = quadSum_(r);
      if (kc == 0) bufR[wslot] = r;
      __syncthreads();
    }

    #pragma unroll
    for (int tc = 0; tc < 8; tc++){
      // w_{t+1} (row tc+1; row 8 == next chunk's row 0, so rotation survives
      // the chunk boundary — sW9 is re-published only after these reads)
      float wn[13];
      #pragma unroll
      for (int i = 0; i < 13; i++) wn[i] = sW9[(tc+1)*52 + m0 + i];

      // ---- stage F: f = tanh(read @ f_Wr.T + fpre); r0/r1 off-path ----
      float r0 = 0.f, r1 = 0.f;
      {
        const float4* x4 = reinterpret_cast<const float4*>(&bufR[kc*36]);
        float a0=0.f,a1=0.f,a2=0.f,a3=0.f;
        #pragma unroll
        for (int i = 0; i < 8; i++){
          float4 xv = x4[i];
          a0 += xv.x*wf[4*i]; a1 += xv.y*wf[4*i+1]; a2 += xv.z*wf[4*i+2]; a3 += xv.w*wf[4*i+3];
        }
        #pragma unroll
        for (int i = 0; i < 13; i++){
          r0 += wn[i]*mv[i];
          r1 += (wn[i]*wreg[i])*mv[i];
        }
        float s = quadSum_((a0+a1)+(a2+a3));
        float fval = fast_tanh_(s + sF8[tc*128 + dd]);
        if (kc == 0){
          bufF[wslot] = fval;
          fO8[tc*128 + dd] = fval;
        }
        r0 = quadSum_(r0); r1 = quadSum_(r1);
      }
      __syncthreads();   // B

      // ---- stage EA: e,a from f; read_{t+1}; mv update ----
      {
        const float4* x4 = reinterpret_cast<const float4*>(&bufF[kc*36]);
        float e0=0.f,e1=0.f,g0=0.f,g1=0.f;
        #pragma unroll
        for (int i = 0; i < 8; i++){
          float4 xv = x4[i];
          e0 += xv.x*ge[4*i];   e1 += xv.y*ge[4*i+1];
          e0 += xv.z*ge[4*i+2]; e1 += xv.w*ge[4*i+3];
          g0 += xv.x*ga[4*i];   g1 += xv.y*ga[4*i+1];
          g0 += xv.z*ga[4*i+2]; g1 += xv.w*ga[4*i+3];
        }
        float ep = quadSum_(e0 + e1);
        float ap = quadSum_(g0 + g1);
        float e_d = fast_sig_(ep + sEA8[tc*256 + dd]);
        float a_d = fast_tanh_(ap + sEA8[tc*256 + 128 + dd]);
        if (kc == 0) bufR[wslot] = r0 - e_d*r1 + a_d*sS8[tc];   // read_{t+1}
        #pragma unroll
        for (int i = 0; i < 13; i++){
          float wv = wreg[i];
          mv[i] = mv[i]*(1.f - wv*e_d) + wv*a_d;
        }
      }
      #pragma unroll
      for (int i = 0; i < 13; i++) wreg[i] = wn[i];   // free under full unroll
      __syncthreads();   // C
    }
  }

  if (tid < 256){
    float4 v = reinterpret_cast<const float4*>(fO8)[tid];
    reinterpret_cast<float4*>(&fAll[(base + TT - 8)*DD])[tid] = v;
  }
}

// ---------------------------------------------------------------------------
// Kernel D: gpre GEMM (unchanged).
// ---------------------------------------------------------------------------
__global__ __launch_bounds__(256) void kGate(
    const float* __restrict__ fAll, const float* __restrict__ Wih,
    const float* __restrict__ bih, const float* __restrict__ bhh,
    float* __restrict__ gpre)
{
  const int jt = blockIdx.x;
  const int rt = blockIdx.y;
  const int tid = threadIdx.x;
  __shared__ float sW[64*129];
  __shared__ float sF[32*129];
  for (int i = tid; i < 64*128; i += 256){
    int jj = i >> 7, k = i & 127;
    sW[jj*129 + k] = Wih[(size_t)(jt*64 + jj)*128 + k];
  }
  for (int i = tid; i < 32*128; i += 256){
    int rr = i >> 7, k = i & 127;
    sF[rr*129 + k] = fAll[(size_t)(rt*32 + rr)*128 + k];
  }
  __syncthreads();
  const int jq = tid & 31, rq = tid >> 5;
  float acc[4][2];
  #pragma unroll
  for (int a = 0; a < 4; a++){ acc[a][0] = 0.f; acc[a][1] = 0.f; }
  for (int k = 0; k < 128; k++){
    float fv[4], wv[2];
    #pragma unroll
    for (int a = 0; a < 4; a++) fv[a] = sF[(rq*4 + a)*129 + k];
    wv[0] = sW[(jq*2 + 0)*129 + k];
    wv[1] = sW[(jq*2 + 1)*129 + k];
    #pragma unroll
    for (int a = 0; a < 4; a++){ acc[a][0] += fv[a]*wv[0]; acc[a][1] += fv[a]*wv[1]; }
  }
  #pragma unroll
  for (int a = 0; a < 4; a++){
    int rowi = rt*32 + rq*4 + a;
    #pragma unroll
    for (int c = 0; c < 2; c++){
      int j = jt*64 + jq*2 + c;
      gpre[(size_t)rowi*512 + j] = acc[a][c] + bih[j] + bhh[j];
    }
  }
}

// ---------------------------------------------------------------------------
// Kernel C (R6): LSTM, chunked + unroll 8, single gbuf, fast gates,
// waves_per_eu(2,2) so whh[4][32] stays in real VGPRs.
// ---------------------------------------------------------------------------
__global__ __launch_bounds__(512, 2) __attribute__((amdgpu_waves_per_eu(2, 2)))
void kLstm(
    const float* __restrict__ gpre, const int* __restrict__ prevA,
    const float* __restrict__ Whh,
    float* __restrict__ Hh, float* __restrict__ Ch)
{
  const int b = blockIdx.x, tid = threadIdx.x;
  const int jo = tid >> 2, kc = tid & 3;
  const int wslot = (jo >> 5)*36 + (jo & 31);

  float whh[4][32];
  #pragma unroll
  for (int g = 0; g < 4; g++){
    const float4* W4 = reinterpret_cast<const float4*>(&Whh[(size_t)(g*128 + jo)*128 + kc*32]);
    #pragma unroll
    for (int i = 0; i < 8; i++){
      float4 v = W4[i];
      whh[g][4*i] = v.x; whh[g][4*i+1] = v.y; whh[g][4*i+2] = v.z; whh[g][4*i+3] = v.w;
    }
  }

  __shared__ __align__(16) float xh[2][144];   // padded h_in broadcast (double buffer)
  __shared__ __align__(16) float gbuf[8*512];  // 16 KB gpre chunk (single buffer)
  __shared__ int spv[TT];

  const size_t base = (size_t)b*TT;
  float4 gr0, gr1;
  {
    const float4* g0 = reinterpret_cast<const float4*>(&gpre[base*512]);
    gr0 = g0[tid*2]; gr1 = g0[tid*2+1];
    spv[tid] = prevA[base + tid];
    if (tid < DD) xh[0][(tid >> 5)*36 + (tid & 31)] = 0.f;
  }

  float cin_cur = 0.f;   // c_in for current step (selected at end of prev step)

  for (int ch = 0; ch < TT/8; ch++){
    const int t0 = ch*8;
    if (ch) __syncthreads();           // prev chunk's gbuf reads + xh writes done
    {
      float4* gb4 = reinterpret_cast<float4*>(gbuf);
      gb4[tid*2] = gr0; gb4[tid*2+1] = gr1;
      if (t0 + 8 < TT){
        const float4* gp4 = reinterpret_cast<const float4*>(&gpre[(base + t0 + 8)*512]);
        gr0 = gp4[tid*2]; gr1 = gp4[tid*2+1];
      }
    }
    __syncthreads();                   // chunk published (+ xh ready for tc=0)

    #pragma unroll
    for (int tc = 0; tc < 8; tc++){
      const int t = t0 + tc, p = t & 1;
      if (tc) __syncthreads();         // xh[p] ready

      // early prefetch of skip state for t+1 (consumed at end of this step)
      int pv2 = -1; float preH = 0.f, preC = 0.f;
      if (t + 1 < TT){
        pv2 = spv[t + 1];
        if (pv2 >= 0 && pv2 < t){
          preH = Hh[(base + pv2)*DD + jo];
          preC = Ch[(base + pv2)*DD + jo];
        }
      }

      float gp0 = gbuf[tc*512 + jo];
      float gp1 = gbuf[tc*512 + 128 + jo];
      float gp2 = gbuf[tc*512 + 256 + jo];
      float gp3 = gbuf[tc*512 + 384 + jo];

      float a0=0.f,a1=0.f,a2=0.f,a3=0.f;
      {
        const float4* x4 = reinterpret_cast<const float4*>(&xh[p][kc*36]);
        #pragma unroll
        for (int i = 0; i < 8; i++){
          float4 xv = x4[i];
          a0 += xv.x*whh[0][4*i]; a0 += xv.y*whh[0][4*i+1]; a0 += xv.z*whh[0][4*i+2]; a0 += xv.w*whh[0][4*i+3];
          a1 += xv.x*whh[1][4*i]; a1 += xv.y*whh[1][4*i+1]; a1 += xv.z*whh[1][4*i+2]; a1 += xv.w*whh[1][4*i+3];
          a2 += xv.x*whh[2][4*i]; a2 += xv.y*whh[2][4*i+1]; a2 += xv.z*whh[2][4*i+2]; a2 += xv.w*whh[2][4*i+3];
          a3 += xv.x*whh[3][4*i]; a3 += xv.y*whh[3][4*i+1]; a3 += xv.z*whh[3][4*i+2]; a3 += xv.w*whh[3][4*i+3];
        }
      }
      a0 = quadSum_(a0); a1 = quadSum_(a1); a2 = quadSum_(a2); a3 = quadSum_(a3);

      const float ig = gp0 + a0, fg = gp1 + a1, gg = gp2 + a2, og = gp3 + a3;
      const float cn = fast_sig_(fg)*cin_cur + fast_sig_(ig)*fast_tanh_(gg);
      const float hn = fast_sig_(og)*fast_tanh_(cn);

      if (kc == 0){
        Hh[(base + t)*DD + jo] = hn;
        Ch[(base + t)*DD + jo] = cn;
      }

      float hin_n, cin_n;
      if (pv2 < 0 || pv2 >= t){ hin_n = hn; cin_n = cn; }       // carry
      else                     { hin_n = preH; cin_n = preC; }   // skip (prefetched)
      if (kc == 0) xh[1 - p][wslot] = hin_n;
      cin_cur = cin_n;
    }
  }
}

// ---------------------------------------------------------------------------
// Kernel E: output head (unchanged except fast sigmoid).
// ---------------------------------------------------------------------------
__global__ __launch_bounds__(256) void kOut(
    const float* __restrict__ Hh, const float* __restrict__ p_W,
    const float* __restrict__ p_b, float* __restrict__ out)
{
  const int row = blockIdx.x*16 + (threadIdx.x >> 4);
  const int l = threadIdx.x & 15;
  const float4* h4 = reinterpret_cast<const float4*>(&Hh[(size_t)row*DD + l*8]);
  const float4* w4 = reinterpret_cast<const float4*>(&p_W[l*8]);
  float4 ha = h4[0], hb = h4[1], wa = w4[0], wb = w4[1];
  float s = ha.x*wa.x + ha.y*wa.y + ha.z*wa.z + ha.w*wa.w
          + hb.x*wb.x + hb.y*wb.y + hb.z*wb.z + hb.w*wb.w;
  s += __shfl_xor(s, 1); s += __shfl_xor(s, 2);
  s += __shfl_xor(s, 4); s += __shfl_xor(s, 8);
  if (l == 0) out[row] = sigmoidf_(s + p_b[0]);
}

// ---------------------------------------------------------------------------
// Launch.
// ---------------------------------------------------------------------------
extern "C" void kernel_launch(void* const* d_in, const int* in_sizes, int n_in,
                              void* d_out, int out_size, void* d_ws, size_t ws_size,
                              hipStream_t stream) {
  const int*   q     = (const int*)  d_in[0];
  const int*   r     = (const int*)  d_in[1];
  const float* k_emb = (const float*)d_in[2];
  const float* Mk    = (const float*)d_in[3];
  const float* Mv0   = (const float*)d_in[4];
  const float* f_W   = (const float*)d_in[5];
  const float* f_b   = (const float*)d_in[6];
  const float* a_W   = (const float*)d_in[7];
  const float* a_b   = (const float*)d_in[8];
  const float* e_W   = (const float*)d_in[9];
  const float* e_b   = (const float*)d_in[10];
  const float* add_W = (const float*)d_in[11];
  const float* add_b = (const float*)d_in[12];
  const float* Wih   = (const float*)d_in[13];
  const float* Whh   = (const float*)d_in[14];
  const float* bih   = (const float*)d_in[15];
  const float* bhh   = (const float*)d_in[16];
  const float* p_W   = (const float*)d_in[17];
  const float* p_b   = (const float*)d_in[18];
  float* out = (float*)d_out;

  char* ws = (char*)d_ws;
  size_t off = 0;
  auto alloc = [&](size_t bytes) -> char* {
    char* p = ws + off;
    off += (bytes + 255) & ~(size_t)255;
    return p;
  };
  float* wAll  = (float*)alloc((size_t)BB*TT*MM*4);
  float* fpre  = (float*)alloc((size_t)BB*TT*DD*4);
  float* ypre  = (float*)alloc((size_t)BB*TT*DD*4);
  float* fAll  = (float*)alloc((size_t)BB*TT*DD*4);
  float* gpre  = (float*)alloc((size_t)BB*TT*512*4);
  float* Hh    = (float*)alloc((size_t)BB*TT*DD*4);
  float* Ch    = (float*)alloc((size_t)BB*TT*DD*4);
  ull*   keyLo = (ull*)  alloc((size_t)BB*TT*8);
  ull*   keyHi = (ull*)  alloc((size_t)BB*TT*8);
  int*   prevA = (int*)  alloc((size_t)BB*TT*4);
  float* Ge    = (float*)alloc((size_t)DD*DD*4);
  float* Ga    = (float*)alloc((size_t)DD*DD*4);
  float* ssAll = (float*)alloc((size_t)BB*TT*4);
  // eapre aliases gpre: lifetimes are disjoint
  // (eapre: [kEA, kMem]; gpre: [kGate, kLstm]).
  float* eapre = gpre;
  (void)ws_size; (void)in_sizes; (void)n_in; (void)out_size;

  kPre  <<<dim3(16, 32), 256, 0, stream>>>(q, r, k_emb, Mk, f_W, f_b, a_W, a_b,
                                           wAll, keyLo, keyHi, fpre, ypre);
  kWW   <<<128, 128, 0, stream>>>(e_W, add_W, a_W, Ge, Ga);
  kEA   <<<dim3(4, 512), 256, 0, stream>>>(ypre, e_W, add_W, e_b, add_b, eapre);
  kSS   <<<32, 512, 0, stream>>>(wAll, ssAll);
  kMatch<<<32, 512, 0, stream>>>(keyLo, keyHi, prevA);
  kMem  <<<32, 512, 0, stream>>>(wAll, fpre, eapre, f_W, Ge, Ga, Mv0, ssAll, fAll);
  kGate <<<dim3(8, 512), 256, 0, stream>>>(fAll, Wih, bih, bhh, gpre);
  kLstm <<<32, 512, 0, stream>>>(gpre, prevA, Whh, Hh, Ch);
  kOut  <<<(BB*TT)/16, 256, 0, stream>>>(Hh, p_W, p_b, out);
}